// Round 4
// baseline (216.431 us; speedup 1.0000x reference)
//
#include <hip/hip_runtime.h>
#include <stdint.h>

#define NUM_KP 17
#define BATCH  32
#define HDIM   256
#define WDIM   256
#define NCH    (BATCH * NUM_KP)     // 544 channels
#define MAXP   30
#define QBLKS  8                    // eighth-channels -> 4352 blocks = exactly 17/CU
#define K1THREADS 256               // 4 waves/block, 8 rows/wave
#define SEGCAP 320                  // per-wave candidate segment (E~205, +8.4 sigma)
#define NPART  (QBLKS * MAXP)       // 240 partial keys per channel

// 12-bit score quantization: q = (float_bits >> 13) - QB, clamped [1, 4095].
#define NBINS  4096
#define QB     125953               // (0x3F800000 >> 13) - 4095

// ws: 4352 blocks x 30 keys x 8 B = 1044 KB of partial top-30 keys.
#define WS_REQUIRED ((size_t)NCH * QBLKS * MAXP * 8)

__device__ __forceinline__ unsigned quant12(float v) {
    int b = (int)(__float_as_uint(v) >> 13) - QB;
    b = b < 1 ? 1 : (b > NBINS - 1 ? NBINS - 1 : b);
    return (unsigned)b;
}

// ---- Kernel 1: eighth-channel NMS + partial exact top-30 -> ws keys ----
// LDS ~= 5.1K seg + 8K hist + 1K gsum + 2K ref + ctl ~= 16.0 KB.
// Residency: wave-capped at 8 blocks/CU (32/32 waves); grid 4352 = 17/CU exactly
// -> no ragged tail (round-3 counters: 53% occupancy, 12% HBM = tail imbalance).
// NO cross-block communication, NO device-scope fences (round-1 lesson: each
// __threadfence invalidates per-XCD L2 -> 4x slowdown from cache thrash).
__global__ __launch_bounds__(K1THREADS, 8)
void pose_part_kernel(const float* __restrict__ heat, unsigned long long* __restrict__ part) {
    __shared__ unsigned s_buf[4 * SEGCAP];       // (q12 << 16) | pixel_idx, per-wave segments
    __shared__ unsigned s_hist[NBINS / 2];       // packed u16 pairs
    __shared__ int s_gsum[256];                  // each = sum of 16 bins
    __shared__ unsigned long long s_ref[256];    // exact survivor keys
    __shared__ int s_wcnt[4];
    __shared__ int s_nref, s_tau;

    const int tid  = threadIdx.x;
    const int chan = blockIdx.x >> 3;
    const int qtr  = blockIdx.x & 7;
    const int wave = tid >> 6;
    const int lane = tid & 63;
    const float NEGINF = -__builtin_inff();
    const float* __restrict__ cp = heat + (size_t)chan * (HDIM * WDIM);

    for (int i = tid; i < NBINS / 2; i += K1THREADS) s_hist[i] = 0;
    if (tid == 0) s_nref = 0;
    __syncthreads();

    // ---- Phase 1: NMS over this wave's 8 rows (2 groups of 4, 1-group prefetch) ----
    const int r0 = (qtr << 5) + (wave << 3);
    const float* colp = cp + (lane << 2);
    const float4 NEG4 = make_float4(NEGINF, NEGINF, NEGINF, NEGINF);
    const unsigned long long ltmask = (1ull << lane) - 1ull;
    unsigned* __restrict__ seg = s_buf + wave * SEGCAP;
    int wavecnt = 0;

    auto LD = [&](int r) -> float4 {
        return (r >= 0 && r < HDIM) ? *(const float4*)(colp + (r << 8)) : NEG4;
    };
    auto push = [&](float v, int pidx, int pos) {
        if (pos < SEGCAP) {
            unsigned q = quant12(v);
            seg[pos] = (q << 16) | (unsigned)pidx;
            atomicAdd(&s_hist[q >> 1], 1u << ((q & 1) << 4));  // fire-and-forget
        }
    };
    auto process = [&](const float4& up, const float4& md, const float4& dn, int r) {
        float vm0 = fmaxf(up.x, fmaxf(md.x, dn.x));
        float vm1 = fmaxf(up.y, fmaxf(md.y, dn.y));
        float vm2 = fmaxf(up.z, fmaxf(md.z, dn.z));
        float vm3 = fmaxf(up.w, fmaxf(md.w, dn.w));
        float left  = __shfl_up(vm3, 1);   if (lane == 0)  left  = NEGINF;
        float right = __shfl_down(vm0, 1); if (lane == 63) right = NEGINF;
        float h0 = fmaxf(left, fmaxf(vm0, vm1));
        float h1 = fmaxf(vm0, fmaxf(vm1, vm2));
        float h2 = fmaxf(vm1, fmaxf(vm2, vm3));
        float h3 = fmaxf(vm2, fmaxf(vm3, right));

        bool p0 = md.x > 0.1f && md.x == h0;
        bool p1 = md.y > 0.1f && md.y == h1;
        bool p2 = md.z > 0.1f && md.z == h2;
        bool p3 = md.w > 0.1f && md.w == h3;
        unsigned long long b0 = __ballot(p0), b1 = __ballot(p1);
        unsigned long long b2 = __ballot(p2), b3 = __ballot(p3);
        int c0 = __popcll(b0), c1 = __popcll(b1), c2 = __popcll(b2);
        int before = wavecnt;
        wavecnt += c0 + c1 + c2 + __popcll(b3);   // wave-uniform

        const int base = (r << 8) | (lane << 2);
        if (p0) push(md.x, base + 0, before + __popcll(b0 & ltmask));
        if (p1) push(md.y, base + 1, before + c0 + __popcll(b1 & ltmask));
        if (p2) push(md.z, base + 2, before + c0 + c1 + __popcll(b2 & ltmask));
        if (p3) push(md.w, base + 3, before + c0 + c1 + c2 + __popcll(b3 & ltmask));
    };

    float4 rm   = LD(r0 - 1);
    float4 cur0 = LD(r0 + 0), cur1 = LD(r0 + 1), cur2 = LD(r0 + 2), cur3 = LD(r0 + 3);
    #pragma unroll
    for (int g = 0; g < 2; ++g) {
        const int rb = r0 + (g << 2);
        float4 n0, n1, n2, n3;
        if (g < 1) { n0 = LD(rb + 4); n1 = LD(rb + 5); n2 = LD(rb + 6); n3 = LD(rb + 7); }
        else       { n0 = LD(rb + 4); n1 = NEG4; n2 = NEG4; n3 = NEG4; }
        process(rm,   cur0, cur1, rb + 0);
        process(cur0, cur1, cur2, rb + 1);
        process(cur1, cur2, cur3, rb + 2);
        process(cur2, cur3, n0,   rb + 3);
        rm = cur3; cur0 = n0; cur1 = n1; cur2 = n2; cur3 = n3;
    }
    if (lane == 0) s_wcnt[wave] = wavecnt < SEGCAP ? wavecnt : SEGCAP;
    __syncthreads();

    // ---- Phase 2: parallel suffix scan -> bin threshold tau (rank MAXP) ----
    {
        int s = 0;
        #pragma unroll
        for (int j = 0; j < 8; ++j) {
            unsigned w = s_hist[tid * 8 + j];
            s += (int)(w & 0xFFFFu) + (int)(w >> 16);
        }
        s_gsum[tid] = s;
    }
    __syncthreads();
    if (wave == 0) {            // one-wave suffix scan over 256 group sums
        int u0 = s_gsum[(lane << 2) + 0], u1 = s_gsum[(lane << 2) + 1];
        int u2 = s_gsum[(lane << 2) + 2], u3 = s_gsum[(lane << 2) + 3];
        int t = u0 + u1 + u2 + u3;
        int R = t;
        #pragma unroll
        for (int off = 1; off < 64; off <<= 1) {
            int v = __shfl_down(R, off);
            if (lane + off < 64) R += v;
        }
        int E = R - t;                       // sum over lanes > me
        int sg3 = u3 + E, sg2 = u2 + sg3, sg1 = u1 + sg2, sg0 = u0 + sg1;
        unsigned long long mask = __ballot(sg0 >= MAXP);
        if (mask == 0ull) {
            if (lane == 0) s_tau = 0;        // fewer than MAXP total -> collect all
        } else {
            int hi = 63 - __builtin_clzll(mask);
            if (lane == hi) {
                int k, above;
                if      (sg3 >= MAXP) { k = 3; above = E;   }
                else if (sg2 >= MAXP) { k = 2; above = sg3; }
                else if (sg1 >= MAXP) { k = 1; above = sg2; }
                else                  { k = 0; above = sg1; }
                int g = (lane << 2) + k;
                int cum = above, tau = 0;
                for (int b = (g << 4) + 15; b >= (g << 4); --b) {
                    cum += (int)((s_hist[b >> 1] >> ((b & 1) << 4)) & 0xFFFFu);
                    if (cum >= MAXP) { tau = b; break; }
                }
                s_tau = tau;
            }
        }
    }
    __syncthreads();

    // ---- Phase 3: collect survivors (q >= tau), re-read exact scores ----
    const unsigned tau = (unsigned)s_tau;
    for (int s = 0; s < 4; ++s) {
        const int c = s_wcnt[s];
        const unsigned* sb = s_buf + s * SEGCAP;
        for (int i = tid; i < c; i += K1THREADS) {
            unsigned p = sb[i];
            if ((p >> 16) >= tau) {
                int pos = atomicAdd(&s_nref, 1);
                if (pos < 256) {
                    unsigned idx = p & 0xFFFFu;
                    float sc = cp[idx];
                    // key: higher score wins; tie -> smaller idx (matches lax.top_k)
                    s_ref[pos] = ((unsigned long long)__float_as_uint(sc) << 32) | (unsigned)(~idx);
                }
            }
        }
    }
    __syncthreads();
    const int nref = s_nref < 256 ? s_nref : 256;

    // ---- Phase 4: rank-by-count partial top-30 -> ws keys (sorted desc) ----
    // Keys are unique (idx embedded), so rank = #{keys > k} is exact and
    // collision-free; all survivor threads count in parallel via LDS broadcast.
    // Rank writes (< nref) and empty-slot zero-fills (>= nref) are disjoint.
    unsigned long long* __restrict__ pk = part + (size_t)blockIdx.x * MAXP;
    if (tid < nref) {
        unsigned long long k = s_ref[tid];
        int rank = 0;
        for (int j = 0; j < nref; ++j) rank += (int)(s_ref[j] > k);
        if (rank < MAXP) pk[rank] = k;
    } else if (tid < MAXP) {
        pk[tid] = 0ull;                      // 0 = empty slot
    }
}

// ---- Kernel 2: merge 8 x 30 partial keys per channel -> final outputs ----
// Rank-by-count over the 240 staged keys: one LDS stage + 240-iteration
// broadcast count per thread.
__global__ __launch_bounds__(256)
void pose_merge_kernel(const unsigned long long* __restrict__ part,
                       float* __restrict__ out, int out_size) {
    __shared__ unsigned long long s_mk[NPART];
    __shared__ int s_nv;
    const int chan = blockIdx.x;
    const int tid  = threadIdx.x;
    const float NEGINF = -__builtin_inff();

    if (tid < NPART) s_mk[tid] = part[(size_t)chan * NPART + tid];
    if (tid == 0) s_nv = 0;
    __syncthreads();

    unsigned long long mk = (tid < NPART) ? s_mk[tid] : 0ull;
    if (mk != 0ull) {
        atomicAdd(&s_nv, 1);
        int rank = 0;
        for (int j = 0; j < NPART; ++j) rank += (int)(s_mk[j] > mk);
        if (rank < MAXP) {
            float sc = __uint_as_float((unsigned)(mk >> 32));
            unsigned idx = (~(unsigned)mk) & 0xFFFFu;
            int x = (int)(idx & 255), y = (int)(idx >> 8);
            long long cb = ((long long)chan * MAXP + rank) * 2;
            if (cb + 1 < out_size) {
                out[cb]     = (float)(x * 4);    // (x, y) * STRIDE
                out[cb + 1] = (float)(y * 4);
            }
            long long so = (long long)NCH * MAXP * 2 + (long long)chan * MAXP + rank;
            if (so < out_size) out[so] = sc;
            long long vo = (long long)NCH * MAXP * 3 + (long long)chan * MAXP + rank;
            if (vo < out_size) out[vo] = 1.0f;
        }
    }
    __syncthreads();
    const int nv = s_nv < MAXP ? s_nv : MAXP;    // valid keys this channel
    if (tid >= nv && tid < MAXP) {               // fill empty trailing slots
        long long cb = ((long long)chan * MAXP + tid) * 2;
        if (cb + 1 < out_size) { out[cb] = 0.0f; out[cb + 1] = 0.0f; }
        long long so = (long long)NCH * MAXP * 2 + (long long)chan * MAXP + tid;
        if (so < out_size) out[so] = NEGINF;
        long long vo = (long long)NCH * MAXP * 3 + (long long)chan * MAXP + tid;
        if (vo < out_size) out[vo] = 0.0f;
    }
}

extern "C" void kernel_launch(void* const* d_in, const int* in_sizes, int n_in,
                              void* d_out, int out_size, void* d_ws, size_t ws_size,
                              hipStream_t stream) {
    const float* heat = (const float*)d_in[0];
    float* out = (float*)d_out;
    unsigned long long* part = (unsigned long long*)d_ws;
    hipLaunchKernelGGL(pose_part_kernel, dim3(NCH * QBLKS), dim3(K1THREADS), 0, stream,
                       heat, part);
    hipLaunchKernelGGL(pose_merge_kernel, dim3(NCH), dim3(256), 0, stream,
                       part, out, out_size);
}

// Round 6
// 215.345 us; speedup vs baseline: 1.0050x; 1.0050x over previous
//
#include <hip/hip_runtime.h>
#include <stdint.h>

#define NUM_KP 17
#define BATCH  32
#define HDIM   256
#define WDIM   256
#define NCH    (BATCH * NUM_KP)     // 544 channels
#define MAXP   30
#define QBLKS  8                    // eighth-channels -> 4352 blocks = exactly 17/CU
#define K1THREADS 256               // 4 waves/block, 8 rows/wave
#define SEGCAP 320                  // per-wave candidate segment (E~205, +8.4 sigma)
#define NPART  (QBLKS * MAXP)       // 240 partial keys per channel

// 10-bit score quantization: q = (float_bits >> 15) - QB, clamped [1, 1023].
// Scores in (0.1, 1] -> q in [152, 1023] (~871 occupied bins for ~820
// candidates/block -> ~1/bin; tau-bin spill ~2 extra survivors, exactness
// preserved by re-ranking survivors on exact re-read scores).
#define NBINS  1024
#define QB     31489                // (0x3F800000 >> 15) - 1023

// ws: 4352 blocks x 30 keys x 8 B = 1044 KB of partial top-30 keys.
#define WS_REQUIRED ((size_t)NCH * QBLKS * MAXP * 8)

__device__ __forceinline__ unsigned quant10(float v) {
    int b = (int)(__float_as_uint(v) >> 15) - QB;
    b = b < 1 ? 1 : (b > NBINS - 1 ? NBINS - 1 : b);
    return (unsigned)b;
}

// ---- Kernel 1: eighth-channel NMS + partial exact top-30 -> ws keys ----
// LDS ~= 5.1K seg + 2K hist + 1K gsum + 2K ref + ctl ~= 10.3 KB.
// Residency: wave-capped at 8 blocks/CU (32/32 waves); grid 4352 = 17/CU exactly
// -> no ragged tail (round-3 lesson: 53% occupancy = tail imbalance).
// NO cross-block communication, NO device-scope fences (round-1 lesson: each
// __threadfence invalidates per-XCD L2 -> 4x slowdown from cache thrash).
__global__ __launch_bounds__(K1THREADS, 8)
void pose_part_kernel(const float* __restrict__ heat, unsigned long long* __restrict__ part) {
    __shared__ unsigned s_buf[4 * SEGCAP];       // (q10 << 16) | pixel_idx, per-wave segments
    __shared__ unsigned s_hist[NBINS / 2];       // packed u16 pairs (512 words)
    __shared__ int s_gsum[256];                  // each = sum of 4 bins
    __shared__ unsigned long long s_ref[256];    // exact survivor keys
    __shared__ int s_wcnt[4];
    __shared__ int s_nref, s_tau;

    const int tid  = threadIdx.x;
    const int chan = blockIdx.x >> 3;
    const int qtr  = blockIdx.x & 7;
    const int wave = tid >> 6;
    const int lane = tid & 63;
    const float NEGINF = -__builtin_inff();
    const float* __restrict__ cp = heat + (size_t)chan * (HDIM * WDIM);

    // ---- Phase 1 setup: issue initial row loads BEFORE LDS init (T14
    // issue-early: ~900cy cold-HBM latency hides under zeroing + barrier) ----
    const int r0 = (qtr << 5) + (wave << 3);
    const float* colp = cp + (lane << 2);
    const float4 NEG4 = make_float4(NEGINF, NEGINF, NEGINF, NEGINF);

    auto LD = [&](int r) -> float4 {
        return (r >= 0 && r < HDIM) ? *(const float4*)(colp + (r << 8)) : NEG4;
    };
    float4 rm   = LD(r0 - 1);
    float4 cur0 = LD(r0 + 0), cur1 = LD(r0 + 1), cur2 = LD(r0 + 2), cur3 = LD(r0 + 3);

    // LDS init (2 stores/thread at 1024 bins, was 8 at 4096)
    s_hist[tid]       = 0;
    s_hist[tid + 256] = 0;
    if (tid == 0) s_nref = 0;
    __syncthreads();

    // ---- Phase 1: NMS over this wave's 8 rows (2 groups of 4, 1-group prefetch) ----
    const unsigned long long ltmask = (1ull << lane) - 1ull;
    unsigned* __restrict__ seg = s_buf + wave * SEGCAP;
    int wavecnt = 0;

    auto push = [&](float v, int pidx, int pos) {
        if (pos < SEGCAP) {
            unsigned q = quant10(v);
            seg[pos] = (q << 16) | (unsigned)pidx;
            atomicAdd(&s_hist[q >> 1], 1u << ((q & 1) << 4));  // fire-and-forget
        }
    };
    auto process = [&](const float4& up, const float4& md, const float4& dn, int r) {
        float vm0 = fmaxf(up.x, fmaxf(md.x, dn.x));
        float vm1 = fmaxf(up.y, fmaxf(md.y, dn.y));
        float vm2 = fmaxf(up.z, fmaxf(md.z, dn.z));
        float vm3 = fmaxf(up.w, fmaxf(md.w, dn.w));
        float left  = __shfl_up(vm3, 1);   if (lane == 0)  left  = NEGINF;
        float right = __shfl_down(vm0, 1); if (lane == 63) right = NEGINF;
        float h0 = fmaxf(left, fmaxf(vm0, vm1));
        float h1 = fmaxf(vm0, fmaxf(vm1, vm2));
        float h2 = fmaxf(vm1, fmaxf(vm2, vm3));
        float h3 = fmaxf(vm2, fmaxf(vm3, right));

        bool p0 = md.x > 0.1f && md.x == h0;
        bool p1 = md.y > 0.1f && md.y == h1;
        bool p2 = md.z > 0.1f && md.z == h2;
        bool p3 = md.w > 0.1f && md.w == h3;
        unsigned long long b0 = __ballot(p0), b1 = __ballot(p1);
        unsigned long long b2 = __ballot(p2), b3 = __ballot(p3);
        int c0 = __popcll(b0), c1 = __popcll(b1), c2 = __popcll(b2);
        int before = wavecnt;
        wavecnt += c0 + c1 + c2 + __popcll(b3);   // wave-uniform

        const int base = (r << 8) | (lane << 2);
        if (p0) push(md.x, base + 0, before + __popcll(b0 & ltmask));
        if (p1) push(md.y, base + 1, before + c0 + __popcll(b1 & ltmask));
        if (p2) push(md.z, base + 2, before + c0 + __popcll(b2 & ltmask) + c1);
        if (p3) push(md.w, base + 3, before + c0 + c1 + c2 + __popcll(b3 & ltmask));
    };

    #pragma unroll
    for (int g = 0; g < 2; ++g) {
        const int rb = r0 + (g << 2);
        float4 n0, n1, n2, n3;
        if (g < 1) { n0 = LD(rb + 4); n1 = LD(rb + 5); n2 = LD(rb + 6); n3 = LD(rb + 7); }
        else       { n0 = LD(rb + 4); n1 = NEG4; n2 = NEG4; n3 = NEG4; }
        process(rm,   cur0, cur1, rb + 0);
        process(cur0, cur1, cur2, rb + 1);
        process(cur1, cur2, cur3, rb + 2);
        process(cur2, cur3, n0,   rb + 3);
        rm = cur3; cur0 = n0; cur1 = n1; cur2 = n2; cur3 = n3;
    }
    if (lane == 0) s_wcnt[wave] = wavecnt < SEGCAP ? wavecnt : SEGCAP;
    __syncthreads();

    // ---- Phase 2: parallel suffix scan -> bin threshold tau (rank MAXP) ----
    {
        unsigned w0 = s_hist[tid * 2], w1 = s_hist[tid * 2 + 1];
        s_gsum[tid] = (int)(w0 & 0xFFFFu) + (int)(w0 >> 16)
                    + (int)(w1 & 0xFFFFu) + (int)(w1 >> 16);   // sum of bins [4t,4t+4)
    }
    __syncthreads();
    if (wave == 0) {            // one-wave suffix scan over 256 group sums
        int u0 = s_gsum[(lane << 2) + 0], u1 = s_gsum[(lane << 2) + 1];
        int u2 = s_gsum[(lane << 2) + 2], u3 = s_gsum[(lane << 2) + 3];
        int t = u0 + u1 + u2 + u3;
        int R = t;
        #pragma unroll
        for (int off = 1; off < 64; off <<= 1) {
            int v = __shfl_down(R, off);
            if (lane + off < 64) R += v;
        }
        int E = R - t;                       // sum over lanes > me
        int sg3 = u3 + E, sg2 = u2 + sg3, sg1 = u1 + sg2, sg0 = u0 + sg1;
        unsigned long long mask = __ballot(sg0 >= MAXP);
        if (mask == 0ull) {
            if (lane == 0) s_tau = 0;        // fewer than MAXP total -> collect all
        } else {
            int hi = 63 - __builtin_clzll(mask);
            if (lane == hi) {
                int k, above;
                if      (sg3 >= MAXP) { k = 3; above = E;   }
                else if (sg2 >= MAXP) { k = 2; above = sg3; }
                else if (sg1 >= MAXP) { k = 1; above = sg2; }
                else                  { k = 0; above = sg1; }
                int g = (lane << 2) + k;     // group covers bins [4g, 4g+4)
                int cum = above, tau = 0;
                for (int b = (g << 2) + 3; b >= (g << 2); --b) {
                    cum += (int)((s_hist[b >> 1] >> ((b & 1) << 4)) & 0xFFFFu);
                    if (cum >= MAXP) { tau = b; break; }
                }
                s_tau = tau;
            }
        }
    }
    __syncthreads();

    // ---- Phase 3: collect survivors (q >= tau), re-read exact scores ----
    const unsigned tau = (unsigned)s_tau;
    for (int s = 0; s < 4; ++s) {
        const int c = s_wcnt[s];
        const unsigned* sb = s_buf + s * SEGCAP;
        for (int i = tid; i < c; i += K1THREADS) {
            unsigned p = sb[i];
            if ((p >> 16) >= tau) {
                int pos = atomicAdd(&s_nref, 1);
                if (pos < 256) {
                    unsigned idx = p & 0xFFFFu;
                    float sc = cp[idx];
                    // key: higher score wins; tie -> smaller idx (matches lax.top_k)
                    s_ref[pos] = ((unsigned long long)__float_as_uint(sc) << 32) | (unsigned)(~idx);
                }
            }
        }
    }
    __syncthreads();
    const int nref = s_nref < 256 ? s_nref : 256;

    // ---- Phase 4: rank-by-count partial top-30 -> ws keys (sorted desc) ----
    // Keys are unique (idx embedded), so rank = #{keys > k} is exact and
    // collision-free; all survivor threads count in parallel via LDS broadcast.
    // Rank writes (< nref) and empty-slot zero-fills (>= nref) are disjoint.
    unsigned long long* __restrict__ pk = part + (size_t)blockIdx.x * MAXP;
    if (tid < nref) {
        unsigned long long k = s_ref[tid];
        int rank = 0;
        for (int j = 0; j < nref; ++j) rank += (int)(s_ref[j] > k);
        if (rank < MAXP) pk[rank] = k;
    } else if (tid < MAXP) {
        pk[tid] = 0ull;                      // 0 = empty slot
    }
}

// ---- Kernel 2: merge 8 x 30 partial keys per channel -> final outputs ----
// Rank-by-count over the 240 staged keys: one LDS stage + 240-iteration
// broadcast count per thread.
__global__ __launch_bounds__(256)
void pose_merge_kernel(const unsigned long long* __restrict__ part,
                       float* __restrict__ out, int out_size) {
    __shared__ unsigned long long s_mk[NPART];
    __shared__ int s_nv;
    const int chan = blockIdx.x;
    const int tid  = threadIdx.x;
    const float NEGINF = -__builtin_inff();

    if (tid < NPART) s_mk[tid] = part[(size_t)chan * NPART + tid];
    if (tid == 0) s_nv = 0;
    __syncthreads();

    unsigned long long mk = (tid < NPART) ? s_mk[tid] : 0ull;
    if (mk != 0ull) {
        atomicAdd(&s_nv, 1);
        int rank = 0;
        for (int j = 0; j < NPART; ++j) rank += (int)(s_mk[j] > mk);
        if (rank < MAXP) {
            float sc = __uint_as_float((unsigned)(mk >> 32));
            unsigned idx = (~(unsigned)mk) & 0xFFFFu;
            int x = (int)(idx & 255), y = (int)(idx >> 8);
            long long cb = ((long long)chan * MAXP + rank) * 2;
            if (cb + 1 < out_size) {
                out[cb]     = (float)(x * 4);    // (x, y) * STRIDE
                out[cb + 1] = (float)(y * 4);
            }
            long long so = (long long)NCH * MAXP * 2 + (long long)chan * MAXP + rank;
            if (so < out_size) out[so] = sc;
            long long vo = (long long)NCH * MAXP * 3 + (long long)chan * MAXP + rank;
            if (vo < out_size) out[vo] = 1.0f;
        }
    }
    __syncthreads();
    const int nv = s_nv < MAXP ? s_nv : MAXP;    // valid keys this channel
    if (tid >= nv && tid < MAXP) {               // fill empty trailing slots
        long long cb = ((long long)chan * MAXP + tid) * 2;
        if (cb + 1 < out_size) { out[cb] = 0.0f; out[cb + 1] = 0.0f; }
        long long so = (long long)NCH * MAXP * 2 + (long long)chan * MAXP + tid;
        if (so < out_size) out[so] = NEGINF;
        long long vo = (long long)NCH * MAXP * 3 + (long long)chan * MAXP + tid;
        if (vo < out_size) out[vo] = 0.0f;
    }
}

extern "C" void kernel_launch(void* const* d_in, const int* in_sizes, int n_in,
                              void* d_out, int out_size, void* d_ws, size_t ws_size,
                              hipStream_t stream) {
    const float* heat = (const float*)d_in[0];
    float* out = (float*)d_out;
    unsigned long long* part = (unsigned long long*)d_ws;
    hipLaunchKernelGGL(pose_part_kernel, dim3(NCH * QBLKS), dim3(K1THREADS), 0, stream,
                       heat, part);
    hipLaunchKernelGGL(pose_merge_kernel, dim3(NCH), dim3(256), 0, stream,
                       part, out, out_size);
}

// Round 7
// 209.487 us; speedup vs baseline: 1.0331x; 1.0280x over previous
//
#include <hip/hip_runtime.h>
#include <stdint.h>

#define NUM_KP 17
#define BATCH  32
#define HDIM   256
#define WDIM   256
#define NCH    (BATCH * NUM_KP)     // 544 channels
#define MAXP   30
#define QBLKS  4                    // quarter-channels -> 2176 blocks (R3 best config)
#define K1THREADS 256               // 4 waves/block, 16 rows/wave
#define SEGCAP 640                  // per-wave candidate segment (E~459, +9 sigma)
#define NPART  (QBLKS * MAXP)       // 120 partial keys per channel

// 10-bit score quantization: q = (float_bits >> 15) - QB, clamped [1, 1023].
// Scores in (0.1, 1] -> q in [152, 1023] (~871 occupied bins; ~1640
// candidates/block -> ~1.9/bin; tau-bin spill ~4 extra survivors, exactness
// preserved by re-ranking survivors on exact re-read scores).
#define NBINS  1024
#define QB     31489                // (0x3F800000 >> 15) - 1023

// ws: 2176 blocks x 30 keys x 8 B = 522 KB of partial top-30 keys.
#define WS_REQUIRED ((size_t)NCH * QBLKS * MAXP * 8)

__device__ __forceinline__ unsigned quant10(float v) {
    int b = (int)(__float_as_uint(v) >> 15) - QB;
    b = b < 1 ? 1 : (b > NBINS - 1 ? NBINS - 1 : b);
    return (unsigned)b;
}

// ---- Kernel 1: quarter-channel NMS + partial exact top-30 -> ws keys ----
// LDS ~= 10.2K seg + 2K hist + 1K gsum + 2K ref + ctl ~= 15.4 KB
// -> 8 blocks/CU resident (32/32 waves; R3 had 7 at 22 KB LDS).
// R4/R6 lesson: QBLKS=8 halves per-block work but doubles per-block fixed
// overhead (LDS init, barriers, scan, phase 4) and k2's key count -> timed
// dur_us WORSE by ~5 us despite better replay-k1. Keep QBLKS=4.
// NO cross-block communication, NO device-scope fences (round-1 lesson: each
// __threadfence invalidates per-XCD L2 -> 4x slowdown from cache thrash).
__global__ __launch_bounds__(K1THREADS, 8)
void pose_part_kernel(const float* __restrict__ heat, unsigned long long* __restrict__ part) {
    __shared__ unsigned s_buf[4 * SEGCAP];       // (q10 << 16) | pixel_idx, per-wave segments
    __shared__ unsigned s_hist[NBINS / 2];       // packed u16 pairs (512 words)
    __shared__ int s_gsum[256];                  // each = sum of 4 bins
    __shared__ unsigned long long s_ref[256];    // exact survivor keys
    __shared__ int s_wcnt[4];
    __shared__ int s_nref, s_tau;

    const int tid  = threadIdx.x;
    const int chan = blockIdx.x >> 2;
    const int qtr  = blockIdx.x & 3;
    const int wave = tid >> 6;
    const int lane = tid & 63;
    const float NEGINF = -__builtin_inff();
    const float* __restrict__ cp = heat + (size_t)chan * (HDIM * WDIM);

    // ---- Phase 1 setup: issue initial row loads BEFORE LDS init (T14
    // issue-early: ~900cy cold-HBM latency hides under zeroing + barrier) ----
    const int r0 = (qtr << 6) + (wave << 4);
    const float* colp = cp + (lane << 2);
    const float4 NEG4 = make_float4(NEGINF, NEGINF, NEGINF, NEGINF);

    auto LD = [&](int r) -> float4 {
        return (r >= 0 && r < HDIM) ? *(const float4*)(colp + (r << 8)) : NEG4;
    };
    float4 rm   = LD(r0 - 1);
    float4 cur0 = LD(r0 + 0), cur1 = LD(r0 + 1), cur2 = LD(r0 + 2), cur3 = LD(r0 + 3);

    // LDS init (2 stores/thread at 1024 bins, was 8 at 4096)
    s_hist[tid]       = 0;
    s_hist[tid + 256] = 0;
    if (tid == 0) s_nref = 0;
    __syncthreads();

    // ---- Phase 1: NMS over this wave's 16 rows (4 groups of 4, 1-group prefetch) ----
    const unsigned long long ltmask = (1ull << lane) - 1ull;
    unsigned* __restrict__ seg = s_buf + wave * SEGCAP;
    int wavecnt = 0;

    auto push = [&](float v, int pidx, int pos) {
        if (pos < SEGCAP) {
            unsigned q = quant10(v);
            seg[pos] = (q << 16) | (unsigned)pidx;
            atomicAdd(&s_hist[q >> 1], 1u << ((q & 1) << 4));  // fire-and-forget
        }
    };
    auto process = [&](const float4& up, const float4& md, const float4& dn, int r) {
        float vm0 = fmaxf(up.x, fmaxf(md.x, dn.x));
        float vm1 = fmaxf(up.y, fmaxf(md.y, dn.y));
        float vm2 = fmaxf(up.z, fmaxf(md.z, dn.z));
        float vm3 = fmaxf(up.w, fmaxf(md.w, dn.w));
        float left  = __shfl_up(vm3, 1);   if (lane == 0)  left  = NEGINF;
        float right = __shfl_down(vm0, 1); if (lane == 63) right = NEGINF;
        float h0 = fmaxf(left, fmaxf(vm0, vm1));
        float h1 = fmaxf(vm0, fmaxf(vm1, vm2));
        float h2 = fmaxf(vm1, fmaxf(vm2, vm3));
        float h3 = fmaxf(vm2, fmaxf(vm3, right));

        bool p0 = md.x > 0.1f && md.x == h0;
        bool p1 = md.y > 0.1f && md.y == h1;
        bool p2 = md.z > 0.1f && md.z == h2;
        bool p3 = md.w > 0.1f && md.w == h3;
        unsigned long long b0 = __ballot(p0), b1 = __ballot(p1);
        unsigned long long b2 = __ballot(p2), b3 = __ballot(p3);
        int c0 = __popcll(b0), c1 = __popcll(b1), c2 = __popcll(b2);
        int before = wavecnt;
        wavecnt += c0 + c1 + c2 + __popcll(b3);   // wave-uniform

        const int base = (r << 8) | (lane << 2);
        if (p0) push(md.x, base + 0, before + __popcll(b0 & ltmask));
        if (p1) push(md.y, base + 1, before + c0 + __popcll(b1 & ltmask));
        if (p2) push(md.z, base + 2, before + c0 + c1 + __popcll(b2 & ltmask));
        if (p3) push(md.w, base + 3, before + c0 + c1 + c2 + __popcll(b3 & ltmask));
    };

    #pragma unroll
    for (int g = 0; g < 4; ++g) {
        const int rb = r0 + (g << 2);
        float4 n0, n1, n2, n3;
        if (g < 3) { n0 = LD(rb + 4); n1 = LD(rb + 5); n2 = LD(rb + 6); n3 = LD(rb + 7); }
        else       { n0 = LD(rb + 4); n1 = NEG4; n2 = NEG4; n3 = NEG4; }
        process(rm,   cur0, cur1, rb + 0);
        process(cur0, cur1, cur2, rb + 1);
        process(cur1, cur2, cur3, rb + 2);
        process(cur2, cur3, n0,   rb + 3);
        rm = cur3; cur0 = n0; cur1 = n1; cur2 = n2; cur3 = n3;
    }
    if (lane == 0) s_wcnt[wave] = wavecnt < SEGCAP ? wavecnt : SEGCAP;
    __syncthreads();

    // ---- Phase 2: parallel suffix scan -> bin threshold tau (rank MAXP) ----
    {
        unsigned w0 = s_hist[tid * 2], w1 = s_hist[tid * 2 + 1];
        s_gsum[tid] = (int)(w0 & 0xFFFFu) + (int)(w0 >> 16)
                    + (int)(w1 & 0xFFFFu) + (int)(w1 >> 16);   // sum of bins [4t,4t+4)
    }
    __syncthreads();
    if (wave == 0) {            // one-wave suffix scan over 256 group sums
        int u0 = s_gsum[(lane << 2) + 0], u1 = s_gsum[(lane << 2) + 1];
        int u2 = s_gsum[(lane << 2) + 2], u3 = s_gsum[(lane << 2) + 3];
        int t = u0 + u1 + u2 + u3;
        int R = t;
        #pragma unroll
        for (int off = 1; off < 64; off <<= 1) {
            int v = __shfl_down(R, off);
            if (lane + off < 64) R += v;
        }
        int E = R - t;                       // sum over lanes > me
        int sg3 = u3 + E, sg2 = u2 + sg3, sg1 = u1 + sg2, sg0 = u0 + sg1;
        unsigned long long mask = __ballot(sg0 >= MAXP);
        if (mask == 0ull) {
            if (lane == 0) s_tau = 0;        // fewer than MAXP total -> collect all
        } else {
            int hi = 63 - __builtin_clzll(mask);
            if (lane == hi) {
                int k, above;
                if      (sg3 >= MAXP) { k = 3; above = E;   }
                else if (sg2 >= MAXP) { k = 2; above = sg3; }
                else if (sg1 >= MAXP) { k = 1; above = sg2; }
                else                  { k = 0; above = sg1; }
                int g = (lane << 2) + k;     // group covers bins [4g, 4g+4)
                int cum = above, tau = 0;
                for (int b = (g << 2) + 3; b >= (g << 2); --b) {
                    cum += (int)((s_hist[b >> 1] >> ((b & 1) << 4)) & 0xFFFFu);
                    if (cum >= MAXP) { tau = b; break; }
                }
                s_tau = tau;
            }
        }
    }
    __syncthreads();

    // ---- Phase 3: collect survivors (q >= tau), re-read exact scores ----
    const unsigned tau = (unsigned)s_tau;
    for (int s = 0; s < 4; ++s) {
        const int c = s_wcnt[s];
        const unsigned* sb = s_buf + s * SEGCAP;
        for (int i = tid; i < c; i += K1THREADS) {
            unsigned p = sb[i];
            if ((p >> 16) >= tau) {
                int pos = atomicAdd(&s_nref, 1);
                if (pos < 256) {
                    unsigned idx = p & 0xFFFFu;
                    float sc = cp[idx];
                    // key: higher score wins; tie -> smaller idx (matches lax.top_k)
                    s_ref[pos] = ((unsigned long long)__float_as_uint(sc) << 32) | (unsigned)(~idx);
                }
            }
        }
    }
    __syncthreads();
    const int nref = s_nref < 256 ? s_nref : 256;

    // ---- Phase 4: rank-by-count partial top-30 -> ws keys (sorted desc) ----
    // Keys are unique (idx embedded), so rank = #{keys > k} is exact and
    // collision-free; all survivor threads count in parallel via LDS broadcast.
    // Rank writes (< nref) and empty-slot zero-fills (>= nref) are disjoint.
    unsigned long long* __restrict__ pk = part + (size_t)blockIdx.x * MAXP;
    if (tid < nref) {
        unsigned long long k = s_ref[tid];
        int rank = 0;
        for (int j = 0; j < nref; ++j) rank += (int)(s_ref[j] > k);
        if (rank < MAXP) pk[rank] = k;
    } else if (tid < MAXP) {
        pk[tid] = 0ull;                      // 0 = empty slot
    }
}

// ---- Kernel 2: merge 4 x 30 partial keys per channel -> final outputs ----
// Rank-by-count over the 120 staged keys: one LDS stage + 120-iteration
// broadcast count per thread.
__global__ __launch_bounds__(128)
void pose_merge_kernel(const unsigned long long* __restrict__ part,
                       float* __restrict__ out, int out_size) {
    __shared__ unsigned long long s_mk[NPART];
    __shared__ int s_nv;
    const int chan = blockIdx.x;
    const int tid  = threadIdx.x;
    const float NEGINF = -__builtin_inff();

    if (tid < NPART) s_mk[tid] = part[(size_t)chan * NPART + tid];
    if (tid == 0) s_nv = 0;
    __syncthreads();

    unsigned long long mk = (tid < NPART) ? s_mk[tid] : 0ull;
    if (mk != 0ull) {
        atomicAdd(&s_nv, 1);
        int rank = 0;
        for (int j = 0; j < NPART; ++j) rank += (int)(s_mk[j] > mk);
        if (rank < MAXP) {
            float sc = __uint_as_float((unsigned)(mk >> 32));
            unsigned idx = (~(unsigned)mk) & 0xFFFFu;
            int x = (int)(idx & 255), y = (int)(idx >> 8);
            long long cb = ((long long)chan * MAXP + rank) * 2;
            if (cb + 1 < out_size) {
                out[cb]     = (float)(x * 4);    // (x, y) * STRIDE
                out[cb + 1] = (float)(y * 4);
            }
            long long so = (long long)NCH * MAXP * 2 + (long long)chan * MAXP + rank;
            if (so < out_size) out[so] = sc;
            long long vo = (long long)NCH * MAXP * 3 + (long long)chan * MAXP + rank;
            if (vo < out_size) out[vo] = 1.0f;
        }
    }
    __syncthreads();
    const int nv = s_nv < MAXP ? s_nv : MAXP;    // valid keys this channel
    if (tid >= nv && tid < MAXP) {               // fill empty trailing slots
        long long cb = ((long long)chan * MAXP + tid) * 2;
        if (cb + 1 < out_size) { out[cb] = 0.0f; out[cb + 1] = 0.0f; }
        long long so = (long long)NCH * MAXP * 2 + (long long)chan * MAXP + tid;
        if (so < out_size) out[so] = NEGINF;
        long long vo = (long long)NCH * MAXP * 3 + (long long)chan * MAXP + tid;
        if (vo < out_size) out[vo] = 0.0f;
    }
}

extern "C" void kernel_launch(void* const* d_in, const int* in_sizes, int n_in,
                              void* d_out, int out_size, void* d_ws, size_t ws_size,
                              hipStream_t stream) {
    const float* heat = (const float*)d_in[0];
    float* out = (float*)d_out;
    unsigned long long* part = (unsigned long long*)d_ws;
    hipLaunchKernelGGL(pose_part_kernel, dim3(NCH * QBLKS), dim3(K1THREADS), 0, stream,
                       heat, part);
    hipLaunchKernelGGL(pose_merge_kernel, dim3(NCH), dim3(128), 0, stream,
                       part, out, out_size);
}